// Round 4
// baseline (208.498 us; speedup 1.0000x reference)
//
#include <hip/hip_runtime.h>
#include <stdint.h>

#define TOPK 13
#define NEG_INF_F (-1e30f)
#define EPSF 1e-7f
#define L2EF 1.4426950408889634f
#define LN2F 0.6931471805599453f
#define MAXCAND 2048
#define MAXB_LDS 64

// class_mask may arrive as bool bytes or int32; bytes 1..3 nonzero => bool bytes.
__device__ __forceinline__ int mask_at(const uint8_t* __restrict__ raw, int i) {
    bool as_u8 = (raw[1] | raw[2] | raw[3]) != 0;
    return as_u8 ? (raw[i] != 0) : (((const int*)raw)[i] != 0);
}

__device__ __forceinline__ float iou_pair(float ax1, float ay1, float ax2, float ay2,
                                          float bx1, float by1, float bx2, float by2) {
    float x1 = fmaxf(ax1, bx1), y1 = fmaxf(ay1, by1);
    float x2 = fminf(ax2, bx2), y2 = fminf(ay2, by2);
    float inter = fmaxf(x2 - x1, 0.f) * fmaxf(y2 - y1, 0.f);
    float a1 = (ax2 - ax1) * (ay2 - ay1);
    float a2 = (bx2 - bx1) * (by2 - by1);
    return inter / (a1 + a2 - inter + EPSF);
}

__device__ __forceinline__ float sigmoid_fast(float s) {
    return 1.f / (1.f + exp2f(-s * L2EF));
}
__device__ __forceinline__ float softplus_bce(float s) {   // max(s,0)+log1p(exp(-|s|))
    float t = exp2f(-fabsf(s) * L2EF);
    return fmaxf(s, 0.f) + log2f(1.f + t) * LN2F;
}

// ---- TAL assignment for one (b,m) task, executed by ONE wave.
// Canonical YOLO 640px grid (N==8400: 80x80/40x40/20x20, strides 8/16/32).
// Enumerates rectangular inside-ranges (~106 candidates), per-lane top-13,
// then 13 shuffle-argmax rounds (tie-break: min anchor index -> packed key).
// Claims recorded CONTENTION-FREE into the wave's OWN slot range
// list[(b*M+m)*TOPK + round] = n+1 (0 = empty); atomicMax fire-and-forget.
__device__ __forceinline__ void assign_wave(
    const float* __restrict__ ps, const float* __restrict__ pb,
    const float* __restrict__ gtb, const int* __restrict__ gtl,
    const uint8_t* __restrict__ mraw,
    unsigned long long* __restrict__ best, unsigned* __restrict__ list,
    int B, int N, int C, int M, int t, int lane) {
    int b = t % B;
    int m = t / B;

    int lbl = gtl[b * M + m];
    int lab = min(max(lbl, 0), C - 1);
    if (!((lbl >= 0) && (lbl < C) && (mask_at(mraw, b * C + lab) != 0))) return;

    float4 g = ((const float4*)gtb)[(size_t)b * M + m];

    const int   n0_[3]  = { 0, 6400, 8000 };
    const int   dim_[3] = { 80, 40, 20 };
    const float sv_[3]  = { 8.f, 16.f, 32.f };

    int ix0[3], iy0[3], ww[3], pre[4];
    pre[0] = 0;
#pragma unroll
    for (int l = 0; l < 3; ++l) {
        float s = sv_[l]; int d = dim_[l];
        int ax0 = max(0,     (int)ceilf (g.x / s - 0.5f));
        int ax1 = min(d - 1, (int)floorf(g.z / s - 0.5f));
        int ay0 = max(0,     (int)ceilf (g.y / s - 0.5f));
        int ay1 = min(d - 1, (int)floorf(g.w / s - 0.5f));
        int w = max(0, ax1 - ax0 + 1);
        int h = max(0, ay1 - ay0 + 1);
        ix0[l] = ax0; iy0[l] = ay0; ww[l] = w;
        pre[l + 1] = pre[l] + w * h;
    }
    int tot = pre[3];
    if (tot == 0) return;

    const float* psb = ps + (size_t)b * N * C + lab;
    const float4* pbb = (const float4*)pb + (size_t)b * N;

    float lv[TOPK];
    int   li[TOPK];
#pragma unroll
    for (int j = 0; j < TOPK; ++j) { lv[j] = NEG_INF_F; li[j] = -1; }

    for (int tt = lane; tt < tot; tt += 64) {
        int l = (tt >= pre[1]) + (tt >= pre[2]);
        int r = tt - pre[l];
        int w = ww[l];
        int iy = r / w, ix = r - iy * w;
        int gx = ix0[l] + ix, gy = iy0[l] + iy;
        int n = n0_[l] + gy * dim_[l] + gx;
        float4 p = pbb[n];
        float iou = iou_pair(p.x, p.y, p.z, p.w, g.x, g.y, g.z, g.w);
        float sc = psb[(size_t)n * C];
        float i3 = iou * iou * iou;
        float val = sigmoid_fast(sc) * i3 * i3;   // cls^1 * iou^6, >= 0
        if (val > lv[TOPK - 1]) {
            bool placed = false;
#pragma unroll
            for (int j = TOPK - 1; j >= 1; --j) {
                if (!placed) {
                    if (val > lv[j - 1]) { lv[j] = lv[j - 1]; li[j] = li[j - 1]; }
                    else { lv[j] = val; li[j] = n; placed = true; }
                }
            }
            if (!placed) { lv[0] = val; li[0] = n; }
        }
    }

    unsigned key = 0xFFFFFFFFu - (unsigned)m;   // smaller m wins value ties
    unsigned long long* bb = best + (size_t)b * N;
    unsigned* myslots = list + ((size_t)b * M + m) * TOPK;
    int rounds = min(tot, TOPK);
    for (int p = 0; p < rounds; ++p) {
        float bv = lv[0]; int bn = li[0];
        for (int off = 32; off > 0; off >>= 1) {
            float ov = __shfl_down(bv, off, 64);
            int   on = __shfl_down(bn, off, 64);
            if (ov > bv || (ov == bv && (unsigned)on < (unsigned)bn)) { bv = ov; bn = on; }
        }
        bv = __shfl(bv, 0, 64);
        bn = __shfl(bn, 0, 64);
        if (bn < 0) break;
        if (li[0] == bn) {   // exactly one lane holds the winner (indices unique/lane)
            unsigned long long pk =
                ((unsigned long long)__float_as_uint(lv[0]) << 32) | (unsigned long long)key;
            atomicMax(bb + bn, pk);          // fire-and-forget: no return dependency
            myslots[p] = (unsigned)bn + 1u;  // contention-free claim record
#pragma unroll
            for (int j = 0; j < TOPK - 1; ++j) { lv[j] = lv[j + 1]; li[j] = li[j + 1]; }
            lv[TOPK - 1] = NEG_INF_F; li[TOPK - 1] = -1;
        }
    }
}

// ---- MEGA KERNEL (N==8400): one launch does everything.
// blocks [0, asgb):            assignment (4 wave-tasks/block)      -> a_done++
// blocks [asgb, asgb+nscan):   BCE bulk scan (independent of assign)-> a_done++
//   then the first ceil(cap/256) scan blocks spin until a_done==asgb+nscan
//   (all claims + sigbuf visible), run the compact fg pass (1 entry/thread,
//   dedup via final winner in best), flush via LDS atomics -> b_done++
//   last of the nscan scan blocks finalizes into out.
// Co-residency: 784 blocks @ 40 VGPR / <4KB LDS -> 8 blocks/CU -> 2048 slots;
// spin-wait cannot deadlock. Release = __threadfence (L2 writeback) before
// counter add; acquire = acquire-load spin + __threadfence (L2 inv) after.
__global__ __launch_bounds__(256, 1) void mega_k(
    const float* __restrict__ ps, const float* __restrict__ pb,
    const float* __restrict__ anch, const float* __restrict__ strd,
    const float* __restrict__ bd, const float* __restrict__ gtb,
    const int* __restrict__ gtl, const uint8_t* __restrict__ mraw,
    unsigned long long* __restrict__ best, unsigned* __restrict__ list,
    float* __restrict__ sigbuf, float* __restrict__ partials,
    unsigned* __restrict__ a_done, unsigned* __restrict__ b_done,
    float* __restrict__ out,
    int B, int N, int C, int M, int asgb, int nb, int nscan, int cap) {
    __shared__ int smask[256];
    __shared__ int s_notall;
    __shared__ float sredA[4], sredB[4];
    __shared__ float sacc[MAXB_LDS * 8];
    __shared__ int s_flag;

    if ((int)blockIdx.x < asgb) {
        int t = blockIdx.x * 4 + (threadIdx.x >> 6);
        if (t < B * M)
            assign_wave(ps, pb, gtb, gtl, mraw, best, list,
                        B, N, C, M, t, threadIdx.x & 63);
        __syncthreads();
        if (threadIdx.x == 0) { __threadfence(); atomicAdd(a_done, 1u); }
        return;
    }
    int bi = blockIdx.x - asgb;
    int b = bi / nb;
    int n = (bi % nb) * 256 + threadIdx.x;

    // ---- phase 1: BCE bulk scan ----
    if (threadIdx.x == 0) s_notall = 0;
    __syncthreads();
    for (int c = threadIdx.x; c < C && c < 256; c += 256) {
        int v = mask_at(mraw, b * C + c);
        smask[c] = v;
        if (!v) s_notall = 1;          // benign race: all writers store 1
    }
    __syncthreads();
    bool allm = (s_notall == 0);

    float acc0 = 0.f, acc3 = 0.f;
    if (n < N) {
        const float* psr = ps + ((size_t)b * N + n) * C;
        float bce_sum = 0.f, smax = NEG_INF_F;

        if (C == 80 && allm) {
            // burst: 20 independent dwordx4 loads issued before first use
            const float4* p4 = (const float4*)psr;
            float4 s4[20];
#pragma unroll
            for (int i = 0; i < 20; ++i) s4[i] = p4[i];
#pragma unroll
            for (int i = 0; i < 20; ++i) {
                bce_sum += softplus_bce(s4[i].x) + softplus_bce(s4[i].y) +
                           softplus_bce(s4[i].z) + softplus_bce(s4[i].w);
                smax = fmaxf(smax, fmaxf(fmaxf(s4[i].x, s4[i].y), fmaxf(s4[i].z, s4[i].w)));
            }
        } else if (allm) {
            int c4 = C & ~3;
            for (int c = 0; c < c4; c += 4) {
                float4 s4 = *(const float4*)(psr + c);
                bce_sum += softplus_bce(s4.x) + softplus_bce(s4.y) +
                           softplus_bce(s4.z) + softplus_bce(s4.w);
                smax = fmaxf(smax, fmaxf(fmaxf(s4.x, s4.y), fmaxf(s4.z, s4.w)));
            }
            for (int c = c4; c < C; ++c) {
                float s = psr[c];
                bce_sum += softplus_bce(s);
                smax = fmaxf(smax, s);
            }
        } else {
            for (int c = 0; c < C; ++c) {
                float s = psr[c];
                if (smask[c]) { bce_sum += softplus_bce(s); smax = fmaxf(smax, s); }
            }
        }
        float sg = sigmoid_fast(smax);
        sigbuf[(size_t)b * N + n] = sg;
        acc0 = bce_sum;
        acc3 = sg;
    }

    int lane = threadIdx.x & 63, wid = threadIdx.x >> 6;
    {
        float v0 = acc0, v3 = acc3;
        for (int off = 32; off > 0; off >>= 1) {
            v0 += __shfl_down(v0, off, 64);
            v3 += __shfl_down(v3, off, 64);
        }
        if (lane == 0) { sredA[wid] = v0; sredB[wid] = v3; }
    }
    __syncthreads();
    if (threadIdx.x == 0) {
        atomicAdd(&partials[b * 8 + 0], sredA[0] + sredA[1] + sredA[2] + sredA[3]);
        atomicAdd(&partials[b * 8 + 3], sredB[0] + sredB[1] + sredB[2] + sredB[3]);
        __threadfence();                 // release sigbuf (L2 writeback)
        atomicAdd(a_done, 1u);
    }

    // ---- phase 2 (first ceil(cap/256) scan blocks): compact fg pass ----
    int base = bi * 256;
    bool use_lds = (B <= MAXB_LDS);
    if (base < cap) {
        if (threadIdx.x == 0) {
            int a_target = asgb + nscan;
            while ((int)__hip_atomic_load(a_done, __ATOMIC_ACQUIRE,
                                          __HIP_MEMORY_SCOPE_AGENT) < a_target)
                __builtin_amdgcn_s_sleep(8);
            s_flag = 1;
        }
        __syncthreads();
        __threadfence();                 // acquire: invalidate stale L1/L2

        if (use_lds)
            for (int i = threadIdx.x; i < B * 8; i += 256) sacc[i] = 0.f;
        __syncthreads();

        int idx = base + threadIdx.x;
        bool active = false;
        int fb = 0, fn = 0, mg = 0;
        if (idx < cap) {
            unsigned e = list[idx];
            if (e != 0u) {
                fn = (int)(e - 1u);
                fb = idx / (M * TOPK);
                int m_claim = (idx / TOPK) % M;
                unsigned long long pk = best[(size_t)fb * N + fn];   // final winner
                mg = (int)(0xFFFFFFFFu - (unsigned)(pk & 0xFFFFFFFFull));
                active = (mg == m_claim);   // exactly one claimant matches
            }
        }

        if (active) {
            int lbl = gtl[fb * M + mg];
            int m_lab = min(max(lbl, 0), C - 1);

            // burst the fg-path inputs: bd row (16x dwordx4), pb, gtb, anchor, stride
            const float* bdr = bd + ((size_t)fb * N + fn) * 64;
            const float4* bq4 = (const float4*)bdr;
            float4 bq[16];
#pragma unroll
            for (int i = 0; i < 16; ++i) bq[i] = bq4[i];
            float4 p = ((const float4*)pb)[(size_t)fb * N + fn];
            float4 g = ((const float4*)gtb)[(size_t)fb * M + mg];
            float2 an = ((const float2*)anch)[fn];
            float stv = strd[fn];
            float slab = ps[((size_t)fb * N + fn) * C + m_lab];
            float sg = sigbuf[(size_t)fb * N + fn];

            float ov = iou_pair(p.x, p.y, p.z, p.w, g.x, g.y, g.z, g.w);
            float c0 = -fmaxf(ov, 0.1f) * slab;   // -ps*tgt correction at c==m_lab
            float c2 = sigmoid_fast(slab);
            float c4 = ov;                        // miou_sum (iou(pb, tb=gtb))
            // CIoU(pb, gtb[mg])
            float w1 = p.z - p.x, h1 = p.w - p.y;
            float w2 = g.z - g.x, h2 = g.w - g.y;
            float cw = fmaxf(p.z, g.z) - fminf(p.x, g.x);
            float ch = fmaxf(p.w, g.w) - fminf(p.y, g.y);
            float cc2 = cw * cw + ch * ch + EPSF;
            float dx = g.x + g.z - p.x - p.z;
            float dy = g.y + g.w - p.y - p.w;
            float rho2 = (dx * dx + dy * dy) * 0.25f;
            const float PI = 3.14159265358979323846f;
            float dv = atanf(w2 / (h2 + EPSF)) - atanf(w1 / (h1 + EPSF));
            float v = (4.f / (PI * PI)) * dv * dv;
            float a = v / (v - ov + 1.f + EPSF);
            float c5 = 1.f - (ov - (rho2 / cc2 + v * a));
            // DFL from the register-resident bd row
            float dall[4] = { (an.x - g.x) / stv, (an.y - g.y) / stv,
                              (g.z - an.x) / stv, (g.w - an.y) / stv };
            float dfl = 0.f;
#pragma unroll
            for (int k = 0; k < 4; ++k) {
                float4 q0 = bq[k * 4 + 0], q1 = bq[k * 4 + 1];
                float4 q2 = bq[k * 4 + 2], q3 = bq[k * 4 + 3];
                float mxv = fmaxf(fmaxf(fmaxf(q0.x, q0.y), fmaxf(q0.z, q0.w)),
                                  fmaxf(fmaxf(q1.x, q1.y), fmaxf(q1.z, q1.w)));
                mxv = fmaxf(mxv, fmaxf(fmaxf(fmaxf(q2.x, q2.y), fmaxf(q2.z, q2.w)),
                                        fmaxf(fmaxf(q3.x, q3.y), fmaxf(q3.z, q3.w))));
                float se = exp2f((q0.x - mxv) * L2EF) + exp2f((q0.y - mxv) * L2EF) +
                           exp2f((q0.z - mxv) * L2EF) + exp2f((q0.w - mxv) * L2EF) +
                           exp2f((q1.x - mxv) * L2EF) + exp2f((q1.y - mxv) * L2EF) +
                           exp2f((q1.z - mxv) * L2EF) + exp2f((q1.w - mxv) * L2EF) +
                           exp2f((q2.x - mxv) * L2EF) + exp2f((q2.y - mxv) * L2EF) +
                           exp2f((q2.z - mxv) * L2EF) + exp2f((q2.w - mxv) * L2EF) +
                           exp2f((q3.x - mxv) * L2EF) + exp2f((q3.y - mxv) * L2EF) +
                           exp2f((q3.z - mxv) * L2EF) + exp2f((q3.w - mxv) * L2EF);
                float lse = mxv + log2f(se) * LN2F;
                float d = fminf(fmaxf(dall[k], 0.f), 14.99f);
                int tl = (int)d;
                int tr = min(tl + 1, 15);
                float wl = (float)tr - d;
                float xtl = bdr[k * 16 + tl];   // L1-hot re-read, avoids dyn reg index
                float xtr = bdr[k * 16 + tr];
                dfl += (lse - xtl) * wl + (lse - xtr) * (1.f - wl);
            }
            float accs[7] = { c0, 1.f, c2, -sg, c4, c5, dfl };
            if (use_lds) {
#pragma unroll
                for (int j = 0; j < 7; ++j) atomicAdd(&sacc[fb * 8 + j], accs[j]);
            } else {
#pragma unroll
                for (int j = 0; j < 7; ++j) atomicAdd(&partials[fb * 8 + j], accs[j]);
            }
        }
        __syncthreads();
        if (use_lds)
            for (int i = threadIdx.x; i < B * 8; i += 256)
                if (sacc[i] != 0.f) atomicAdd(&partials[i], sacc[i]);
        __syncthreads();
    }

    // ---- b_done handshake + last-block finalize ----
    if (threadIdx.x == 0) {
        __threadfence();
        unsigned r = atomicAdd(b_done, 1u);
        s_flag = (r == (unsigned)nscan - 1u) ? 1 : 0;
    }
    __syncthreads();
    if (!s_flag) return;
    if (threadIdx.x >= 64) return;
    __threadfence();   // acquire side

    int fl = threadIdx.x;
    float tm = 0, ti = 0, td = 0, tp = 0, tneg = 0, pos = 0, neg = 0, miou = 0;
    for (int s = fl; s < B; s += 64) {
        float vcs = 0.f;
        for (int c = 0; c < C; ++c) vcs += mask_at(mraw, s * C + c) ? 1.f : 0.f;
        const float* pr = partials + s * 8;
        float p0 = __hip_atomic_load(&pr[0], __ATOMIC_RELAXED, __HIP_MEMORY_SCOPE_AGENT);
        float p1 = __hip_atomic_load(&pr[1], __ATOMIC_RELAXED, __HIP_MEMORY_SCOPE_AGENT);
        float p2 = __hip_atomic_load(&pr[2], __ATOMIC_RELAXED, __HIP_MEMORY_SCOPE_AGENT);
        float p3 = __hip_atomic_load(&pr[3], __ATOMIC_RELAXED, __HIP_MEMORY_SCOPE_AGENT);
        float p4 = __hip_atomic_load(&pr[4], __ATOMIC_RELAXED, __HIP_MEMORY_SCOPE_AGENT);
        float p5 = __hip_atomic_load(&pr[5], __ATOMIC_RELAXED, __HIP_MEMORY_SCOPE_AGENT);
        float p6 = __hip_atomic_load(&pr[6], __ATOMIC_RELAXED, __HIP_MEMORY_SCOPE_AGENT);
        float cnt = p1;
        tm += p0 / ((float)N * fmaxf(vcs, 1.f));
        ti += (cnt > 0.f) ? p5 / fmaxf(cnt, 1.f) : 0.f;
        td += (cnt > 0.f) ? p6 / fmaxf(cnt * 4.f, 1.f) : 0.f;
        tp += cnt; tneg += (float)N - cnt;
        pos += p2; neg += p3; miou += p4;
    }
    for (int off = 32; off > 0; off >>= 1) {
        tm += __shfl_down(tm, off, 64);   ti += __shfl_down(ti, off, 64);
        td += __shfl_down(td, off, 64);   tp += __shfl_down(tp, off, 64);
        tneg += __shfl_down(tneg, off, 64); pos += __shfl_down(pos, off, 64);
        neg += __shfl_down(neg, off, 64); miou += __shfl_down(miou, off, 64);
    }
    if (fl == 0) {
        float Bf = (float)B;
        out[0] = (0.5f * tm + 7.5f * ti + 1.5f * td) / Bf;
        out[1] = tm / Bf;
        out[2] = ti / Bf;
        out[3] = td / Bf;
        out[4] = tp;
        out[5] = pos / fmaxf(tp, 1.f);
        out[6] = neg / fmaxf(tneg, 1.f);
        out[7] = miou / fmaxf(tp, 1.f);
    }
}

// ======================= generic fallback path (N != 8400) =======================
__global__ __launch_bounds__(256) void assign_topk_k(
    const float* __restrict__ ps, const float* __restrict__ pb,
    const float* __restrict__ anch, const float* __restrict__ gtb,
    const int* __restrict__ gtl, const uint8_t* __restrict__ mraw,
    unsigned long long* __restrict__ best, int B, int N, int C, int M) {
    int b = blockIdx.x % B;
    int m = blockIdx.x / B;

    __shared__ float cval[MAXCAND];
    __shared__ int   cidx[MAXCAND];
    __shared__ int   scnt;
    if (threadIdx.x == 0) scnt = 0;

    int lbl = gtl[b * M + m];
    int lab = min(max(lbl, 0), C - 1);
    bool valid = (lbl >= 0) && (lbl < C) && (mask_at(mraw, b * C + lab) != 0);
    __syncthreads();

    if (valid) {
        float4 g = ((const float4*)gtb)[(size_t)b * M + m];
        const float* psb = ps + (size_t)b * N * C + lab;
        const float4* pbb = (const float4*)pb + (size_t)b * N;
        for (int n = threadIdx.x; n < N; n += 256) {
            float2 a = ((const float2*)anch)[n];
            if (a.x < g.x || a.x > g.z || a.y < g.y || a.y > g.w) continue;
            float4 p = pbb[n];
            float iou = iou_pair(p.x, p.y, p.z, p.w, g.x, g.y, g.z, g.w);
            float s = psb[(size_t)n * C];
            float i3 = iou * iou * iou;
            float val = sigmoid_fast(s) * i3 * i3;
            int slot = atomicAdd(&scnt, 1);
            if (slot < MAXCAND) { cval[slot] = val; cidx[slot] = n; }
        }
    }
    __syncthreads();
    if (!valid || threadIdx.x >= 64) return;

    int total = min(scnt, MAXCAND);
    if (total == 0) return;
    int lane = threadIdx.x;

    float lv[TOPK];
    int   li[TOPK];
#pragma unroll
    for (int j = 0; j < TOPK; ++j) { lv[j] = NEG_INF_F; li[j] = -1; }
    for (int i = lane; i < total; i += 64) {
        float v = cval[i]; int ix = cidx[i];
        if (v > lv[TOPK - 1]) {
            bool placed = false;
#pragma unroll
            for (int j = TOPK - 1; j >= 1; --j) {
                if (!placed) {
                    if (v > lv[j - 1]) { lv[j] = lv[j - 1]; li[j] = li[j - 1]; }
                    else { lv[j] = v; li[j] = ix; placed = true; }
                }
            }
            if (!placed) { lv[0] = v; li[0] = ix; }
        }
    }

    unsigned key = 0xFFFFFFFFu - (unsigned)m;
    unsigned long long* bb = best + (size_t)b * N;
    int rounds = min(total, TOPK);
    for (int p = 0; p < rounds; ++p) {
        float bv = lv[0]; int bn = li[0];
        for (int off = 32; off > 0; off >>= 1) {
            float ov = __shfl_down(bv, off, 64);
            int   on = __shfl_down(bn, off, 64);
            if (ov > bv || (ov == bv && (unsigned)on < (unsigned)bn)) { bv = ov; bn = on; }
        }
        bv = __shfl(bv, 0, 64);
        bn = __shfl(bn, 0, 64);
        if (bn < 0) break;
        if (li[0] == bn) {
            unsigned long long pk =
                ((unsigned long long)__float_as_uint(lv[0]) << 32) | (unsigned long long)key;
            atomicMax(bb + bn, pk);
#pragma unroll
            for (int j = 0; j < TOPK - 1; ++j) { lv[j] = lv[j + 1]; li[j] = li[j + 1]; }
            lv[TOPK - 1] = NEG_INF_F; li[TOPK - 1] = -1;
        }
    }
}

__global__ __launch_bounds__(256, 1) void per_anchor_k(
    const float* __restrict__ ps, const float* __restrict__ pb,
    const float* __restrict__ anch, const float* __restrict__ strd,
    const float* __restrict__ bd, const float* __restrict__ gtb,
    const int* __restrict__ gtl, const uint8_t* __restrict__ mraw,
    const unsigned long long* __restrict__ best,
    float* __restrict__ partials, int B, int N, int C, int M) {
    int b = blockIdx.y;
    int n = blockIdx.x * 256 + threadIdx.x;

    __shared__ int smask[256];
    __shared__ int s_notall;
    __shared__ float sred[4 * 8];
    if (threadIdx.x == 0) s_notall = 0;
    __syncthreads();
    for (int c = threadIdx.x; c < C && c < 256; c += 256) {
        int v = mask_at(mraw, b * C + c);
        smask[c] = v;
        if (!v) s_notall = 1;
    }
    __syncthreads();
    bool allm = (s_notall == 0);

    float acc0 = 0, acc1 = 0, acc2 = 0, acc3 = 0, acc4 = 0, acc5 = 0, acc6 = 0;

    if (n < N) {
        unsigned long long pk = best[(size_t)b * N + n];
        bool fg = (pk != 0ull);
        int mg = fg ? (int)(0xFFFFFFFFu - (unsigned)(pk & 0xFFFFFFFFull)) : 0;
        int lbl = gtl[b * M + mg];
        int m_lab = min(max(lbl, 0), C - 1);

        const float* psr = ps + ((size_t)b * N + n) * C;
        float bce_sum = 0.f, smax = NEG_INF_F;

        if (C == 80 && allm) {
            const float4* p4 = (const float4*)psr;
            float4 s4[20];
#pragma unroll
            for (int i = 0; i < 20; ++i) s4[i] = p4[i];
#pragma unroll
            for (int i = 0; i < 20; ++i) {
                bce_sum += softplus_bce(s4[i].x) + softplus_bce(s4[i].y) +
                           softplus_bce(s4[i].z) + softplus_bce(s4[i].w);
                smax = fmaxf(smax, fmaxf(fmaxf(s4[i].x, s4[i].y), fmaxf(s4[i].z, s4[i].w)));
            }
        } else if (allm) {
            int c4 = C & ~3;
            for (int c = 0; c < c4; c += 4) {
                float4 s4 = *(const float4*)(psr + c);
                bce_sum += softplus_bce(s4.x) + softplus_bce(s4.y) +
                           softplus_bce(s4.z) + softplus_bce(s4.w);
                smax = fmaxf(smax, fmaxf(fmaxf(s4.x, s4.y), fmaxf(s4.z, s4.w)));
            }
            for (int c = c4; c < C; ++c) {
                float s = psr[c];
                bce_sum += softplus_bce(s);
                smax = fmaxf(smax, s);
            }
        } else {
            for (int c = 0; c < C; ++c) {
                float s = psr[c];
                if (smask[c]) { bce_sum += softplus_bce(s); smax = fmaxf(smax, s); }
            }
        }

        acc1 = fg ? 1.f : 0.f;
        acc3 = fg ? 0.f : sigmoid_fast(smax);

        if (fg) {
            const float* bdr = bd + ((size_t)b * N + n) * 64;
            const float4* bq4 = (const float4*)bdr;
            float4 bq[16];
#pragma unroll
            for (int i = 0; i < 16; ++i) bq[i] = bq4[i];
            float4 p = ((const float4*)pb)[(size_t)b * N + n];
            float4 g = ((const float4*)gtb)[(size_t)b * M + mg];
            float2 an = ((const float2*)anch)[n];
            float stv = strd[n];
            float slab = psr[m_lab];

            float ov = iou_pair(p.x, p.y, p.z, p.w, g.x, g.y, g.z, g.w);
            bce_sum -= fmaxf(ov, 0.1f) * slab;
            acc2 = sigmoid_fast(slab);
            acc4 = ov;
            float w1 = p.z - p.x, h1 = p.w - p.y;
            float w2 = g.z - g.x, h2 = g.w - g.y;
            float cw = fmaxf(p.z, g.z) - fminf(p.x, g.x);
            float ch = fmaxf(p.w, g.w) - fminf(p.y, g.y);
            float c2 = cw * cw + ch * ch + EPSF;
            float dx = g.x + g.z - p.x - p.z;
            float dy = g.y + g.w - p.y - p.w;
            float rho2 = (dx * dx + dy * dy) * 0.25f;
            const float PI = 3.14159265358979323846f;
            float dv = atanf(w2 / (h2 + EPSF)) - atanf(w1 / (h1 + EPSF));
            float v = (4.f / (PI * PI)) * dv * dv;
            float a = v / (v - ov + 1.f + EPSF);
            acc5 = 1.f - (ov - (rho2 / c2 + v * a));
            float dall[4] = { (an.x - g.x) / stv, (an.y - g.y) / stv,
                              (g.z - an.x) / stv, (g.w - an.y) / stv };
            float dfl = 0.f;
#pragma unroll
            for (int k = 0; k < 4; ++k) {
                float4 q0 = bq[k * 4 + 0], q1 = bq[k * 4 + 1];
                float4 q2 = bq[k * 4 + 2], q3 = bq[k * 4 + 3];
                float mxv = fmaxf(fmaxf(fmaxf(q0.x, q0.y), fmaxf(q0.z, q0.w)),
                                  fmaxf(fmaxf(q1.x, q1.y), fmaxf(q1.z, q1.w)));
                mxv = fmaxf(mxv, fmaxf(fmaxf(fmaxf(q2.x, q2.y), fmaxf(q2.z, q2.w)),
                                        fmaxf(fmaxf(q3.x, q3.y), fmaxf(q3.z, q3.w))));
                float se = exp2f((q0.x - mxv) * L2EF) + exp2f((q0.y - mxv) * L2EF) +
                           exp2f((q0.z - mxv) * L2EF) + exp2f((q0.w - mxv) * L2EF) +
                           exp2f((q1.x - mxv) * L2EF) + exp2f((q1.y - mxv) * L2EF) +
                           exp2f((q1.z - mxv) * L2EF) + exp2f((q1.w - mxv) * L2EF) +
                           exp2f((q2.x - mxv) * L2EF) + exp2f((q2.y - mxv) * L2EF) +
                           exp2f((q2.z - mxv) * L2EF) + exp2f((q2.w - mxv) * L2EF) +
                           exp2f((q3.x - mxv) * L2EF) + exp2f((q3.y - mxv) * L2EF) +
                           exp2f((q3.z - mxv) * L2EF) + exp2f((q3.w - mxv) * L2EF);
                float lse = mxv + log2f(se) * LN2F;
                float d = fminf(fmaxf(dall[k], 0.f), 14.99f);
                int tl = (int)d;
                int tr = min(tl + 1, 15);
                float wl = (float)tr - d;
                float xtl = bdr[k * 16 + tl];
                float xtr = bdr[k * 16 + tr];
                dfl += (lse - xtl) * wl + (lse - xtr) * (1.f - wl);
            }
            acc6 = dfl;
        }
        acc0 = bce_sum;
    }

    int lane = threadIdx.x & 63, wid = threadIdx.x >> 6;
    float accs[7] = { acc0, acc1, acc2, acc3, acc4, acc5, acc6 };
#pragma unroll
    for (int j = 0; j < 7; ++j) {
        float v = accs[j];
        for (int off = 32; off > 0; off >>= 1) v += __shfl_down(v, off, 64);
        if (lane == 0) sred[wid * 8 + j] = v;
    }
    __syncthreads();
    if (threadIdx.x < 7) {
        float s = sred[0 * 8 + threadIdx.x] + sred[1 * 8 + threadIdx.x] +
                  sred[2 * 8 + threadIdx.x] + sred[3 * 8 + threadIdx.x];
        atomicAdd(&partials[b * 8 + threadIdx.x], s);
    }
}

__global__ void finalize_k(const float* __restrict__ partials, const uint8_t* __restrict__ mraw,
                           float* __restrict__ out, int B, int N, int C) {
    int lane = threadIdx.x;
    float tm = 0, ti = 0, td = 0, tp = 0, tneg = 0, pos = 0, neg = 0, miou = 0;
    if (lane < B) {
        float vcs = 0.f;
        for (int c = 0; c < C; ++c) vcs += mask_at(mraw, lane * C + c) ? 1.f : 0.f;
        const float* pr = partials + lane * 8;
        float cnt = pr[1];
        tm = pr[0] / ((float)N * fmaxf(vcs, 1.f));
        ti = (cnt > 0.f) ? pr[5] / fmaxf(cnt, 1.f) : 0.f;
        td = (cnt > 0.f) ? pr[6] / fmaxf(cnt * 4.f, 1.f) : 0.f;
        tp = cnt; tneg = (float)N - cnt;
        pos = pr[2]; neg = pr[3]; miou = pr[4];
    }
    for (int off = 32; off > 0; off >>= 1) {
        tm += __shfl_down(tm, off, 64);   ti += __shfl_down(ti, off, 64);
        td += __shfl_down(td, off, 64);   tp += __shfl_down(tp, off, 64);
        tneg += __shfl_down(tneg, off, 64); pos += __shfl_down(pos, off, 64);
        neg += __shfl_down(neg, off, 64); miou += __shfl_down(miou, off, 64);
    }
    if (lane == 0) {
        float Bf = (float)B;
        out[0] = (0.5f * tm + 7.5f * ti + 1.5f * td) / Bf;
        out[1] = tm / Bf;
        out[2] = ti / Bf;
        out[3] = td / Bf;
        out[4] = tp;
        out[5] = pos / fmaxf(tp, 1.f);
        out[6] = neg / fmaxf(tneg, 1.f);
        out[7] = miou / fmaxf(tp, 1.f);
    }
}

extern "C" void kernel_launch(void* const* d_in, const int* in_sizes, int n_in,
                              void* d_out, int out_size, void* d_ws, size_t ws_size,
                              hipStream_t stream) {
    const float* ps   = (const float*)d_in[0];   // (B,N,C)
    const float* pb   = (const float*)d_in[1];   // (B,N,4)
    const float* anch = (const float*)d_in[2];   // (N,2)
    const float* strd = (const float*)d_in[3];   // (N,1)
    const float* bd   = (const float*)d_in[4];   // (B,N,64)
    const float* gtb  = (const float*)d_in[5];   // (B,M,4)
    const int*   gtl  = (const int*)d_in[6];     // (B,M)
    const uint8_t* cmsk = (const uint8_t*)d_in[7]; // (B,C) bool

    int N = in_sizes[2] / 2;
    int B = in_sizes[1] / (4 * N);
    int C = in_sizes[0] / (B * N);
    int M = in_sizes[6] / B;

    // workspace layout: [best | partials | ctrs | list (all zeroed) | sigbuf]
    size_t bestBytes = (size_t)B * N * sizeof(unsigned long long);
    size_t off1 = (bestBytes + 255) & ~(size_t)255;                 // partials
    size_t partBytes = (size_t)B * 8 * sizeof(float);
    size_t off2 = (off1 + partBytes + 255) & ~(size_t)255;          // ctrs
    size_t off3 = off2 + 256;                                       // list
    size_t listBytes = (size_t)B * M * TOPK * sizeof(unsigned);
    size_t zeroBytes = (off3 + listBytes + 255) & ~(size_t)255;
    unsigned long long* best = (unsigned long long*)d_ws;
    float* partials = (float*)((char*)d_ws + off1);
    unsigned int* a_done = (unsigned int*)((char*)d_ws + off2);
    unsigned int* b_done = a_done + 1;
    unsigned int* list = (unsigned int*)((char*)d_ws + off3);
    float* sigbuf = (float*)((char*)d_ws + zeroBytes);              // no init needed

    hipMemsetAsync(d_ws, 0, zeroBytes, stream);

    int nb = (N + 255) / 256;
    if (N == 8400) {
        int asgb = (B * M + 3) / 4;
        int nscan = B * nb;
        int cap = B * M * TOPK;
        mega_k<<<asgb + nscan, 256, 0, stream>>>(ps, pb, anch, strd, bd, gtb, gtl, cmsk,
                                                 best, list, sigbuf, partials,
                                                 a_done, b_done, (float*)d_out,
                                                 B, N, C, M, asgb, nb, nscan, cap);
    } else {
        assign_topk_k<<<B * M, 256, 0, stream>>>(ps, pb, anch, gtb, gtl, cmsk, best, B, N, C, M);
        dim3 gB(nb, B);
        per_anchor_k<<<gB, 256, 0, stream>>>(ps, pb, anch, strd, bd, gtb, gtl, cmsk, best,
                                             partials, B, N, C, M);
        finalize_k<<<1, 64, 0, stream>>>(partials, cmsk, (float*)d_out, B, N, C);
    }
}

// Round 5
// 146.802 us; speedup vs baseline: 1.4203x; 1.4203x over previous
//
#include <hip/hip_runtime.h>
#include <stdint.h>

#define TOPK 13
#define NEG_INF_F (-1e30f)
#define EPSF 1e-7f
#define L2EF 1.4426950408889634f
#define LN2F 0.6931471805599453f
#define MAXCAND 2048
#define MAXB_LDS 64

// class_mask may arrive as bool bytes or int32; bytes 1..3 nonzero => bool bytes.
__device__ __forceinline__ int mask_at(const uint8_t* __restrict__ raw, int i) {
    bool as_u8 = (raw[1] | raw[2] | raw[3]) != 0;
    return as_u8 ? (raw[i] != 0) : (((const int*)raw)[i] != 0);
}

__device__ __forceinline__ float iou_pair(float ax1, float ay1, float ax2, float ay2,
                                          float bx1, float by1, float bx2, float by2) {
    float x1 = fmaxf(ax1, bx1), y1 = fmaxf(ay1, by1);
    float x2 = fminf(ax2, bx2), y2 = fminf(ay2, by2);
    float inter = fmaxf(x2 - x1, 0.f) * fmaxf(y2 - y1, 0.f);
    float a1 = (ax2 - ax1) * (ay2 - ay1);
    float a2 = (bx2 - bx1) * (by2 - by1);
    return inter / (a1 + a2 - inter + EPSF);
}

__device__ __forceinline__ float sigmoid_fast(float s) {
    return 1.f / (1.f + exp2f(-s * L2EF));
}
__device__ __forceinline__ float softplus_bce(float s) {   // max(s,0)+log1p(exp(-|s|))
    float t = exp2f(-fabsf(s) * L2EF);
    return fmaxf(s, 0.f) + log2f(1.f + t) * LN2F;
}

// ---- TAL assignment for one (b,m) task, executed by ONE wave.
// Canonical YOLO 640px grid (N==8400: 80x80/40x40/20x20, strides 8/16/32).
// Enumerates rectangular inside-ranges (~106 candidates), per-lane top-13,
// then 13 shuffle-argmax rounds (tie-break: min anchor index -> packed key).
// Claims recorded CONTENTION-FREE into the wave's OWN slot range
// list[(b*M+m)*TOPK + round] = n+1 (0 = empty); atomicMax fire-and-forget.
__device__ __forceinline__ void assign_wave(
    const float* __restrict__ ps, const float* __restrict__ pb,
    const float* __restrict__ gtb, const int* __restrict__ gtl,
    const uint8_t* __restrict__ mraw,
    unsigned long long* __restrict__ best, unsigned* __restrict__ list,
    int B, int N, int C, int M, int t, int lane) {
    int b = t % B;
    int m = t / B;

    int lbl = gtl[b * M + m];
    int lab = min(max(lbl, 0), C - 1);
    if (!((lbl >= 0) && (lbl < C) && (mask_at(mraw, b * C + lab) != 0))) return;

    float4 g = ((const float4*)gtb)[(size_t)b * M + m];

    const int   n0_[3]  = { 0, 6400, 8000 };
    const int   dim_[3] = { 80, 40, 20 };
    const float sv_[3]  = { 8.f, 16.f, 32.f };

    int ix0[3], iy0[3], ww[3], pre[4];
    pre[0] = 0;
#pragma unroll
    for (int l = 0; l < 3; ++l) {
        float s = sv_[l]; int d = dim_[l];
        int ax0 = max(0,     (int)ceilf (g.x / s - 0.5f));
        int ax1 = min(d - 1, (int)floorf(g.z / s - 0.5f));
        int ay0 = max(0,     (int)ceilf (g.y / s - 0.5f));
        int ay1 = min(d - 1, (int)floorf(g.w / s - 0.5f));
        int w = max(0, ax1 - ax0 + 1);
        int h = max(0, ay1 - ay0 + 1);
        ix0[l] = ax0; iy0[l] = ay0; ww[l] = w;
        pre[l + 1] = pre[l] + w * h;
    }
    int tot = pre[3];
    if (tot == 0) return;

    const float* psb = ps + (size_t)b * N * C + lab;
    const float4* pbb = (const float4*)pb + (size_t)b * N;

    float lv[TOPK];
    int   li[TOPK];
#pragma unroll
    for (int j = 0; j < TOPK; ++j) { lv[j] = NEG_INF_F; li[j] = -1; }

    for (int tt = lane; tt < tot; tt += 64) {
        int l = (tt >= pre[1]) + (tt >= pre[2]);
        int r = tt - pre[l];
        int w = ww[l];
        int iy = r / w, ix = r - iy * w;
        int gx = ix0[l] + ix, gy = iy0[l] + iy;
        int n = n0_[l] + gy * dim_[l] + gx;
        float4 p = pbb[n];
        float iou = iou_pair(p.x, p.y, p.z, p.w, g.x, g.y, g.z, g.w);
        float sc = psb[(size_t)n * C];
        float i3 = iou * iou * iou;
        float val = sigmoid_fast(sc) * i3 * i3;   // cls^1 * iou^6, >= 0
        if (val > lv[TOPK - 1]) {
            bool placed = false;
#pragma unroll
            for (int j = TOPK - 1; j >= 1; --j) {
                if (!placed) {
                    if (val > lv[j - 1]) { lv[j] = lv[j - 1]; li[j] = li[j - 1]; }
                    else { lv[j] = val; li[j] = n; placed = true; }
                }
            }
            if (!placed) { lv[0] = val; li[0] = n; }
        }
    }

    unsigned key = 0xFFFFFFFFu - (unsigned)m;   // smaller m wins value ties
    unsigned long long* bb = best + (size_t)b * N;
    unsigned* myslots = list + ((size_t)b * M + m) * TOPK;
    int rounds = min(tot, TOPK);
    for (int p = 0; p < rounds; ++p) {
        float bv = lv[0]; int bn = li[0];
        for (int off = 32; off > 0; off >>= 1) {
            float ov = __shfl_down(bv, off, 64);
            int   on = __shfl_down(bn, off, 64);
            if (ov > bv || (ov == bv && (unsigned)on < (unsigned)bn)) { bv = ov; bn = on; }
        }
        bv = __shfl(bv, 0, 64);
        bn = __shfl(bn, 0, 64);
        if (bn < 0) break;
        if (li[0] == bn) {   // exactly one lane holds the winner (indices unique/lane)
            unsigned long long pk =
                ((unsigned long long)__float_as_uint(lv[0]) << 32) | (unsigned long long)key;
            atomicMax(bb + bn, pk);          // fire-and-forget: no return dependency
            myslots[p] = (unsigned)bn + 1u;  // contention-free claim record
#pragma unroll
            for (int j = 0; j < TOPK - 1; ++j) { lv[j] = lv[j + 1]; li[j] = li[j + 1]; }
            lv[TOPK - 1] = NEG_INF_F; li[TOPK - 1] = -1;
        }
    }
}

// ---- FUSED KERNEL A: blocks [0, asgb) run assignment (4 wave-tasks/block);
// blocks [asgb, asgb + B*nb) run the assignment-INDEPENDENT BCE bulk scan.
// C==80 fast path: 4-lanes-per-row coalesced reads — lanes 4r..4r+3 read
// adjacent 16B chunks (64B fully-consumed cache lines, 5 independent loads
// in flight per lane, fits the ~40-VGPR budget), then a 2-step shfl_xor
// row-reduce; sigbuf writes coalesce into one 64B segment per wave-pass.
__global__ __launch_bounds__(256, 1) void fused_a_k(
    const float* __restrict__ ps, const float* __restrict__ pb,
    const float* __restrict__ gtb, const int* __restrict__ gtl,
    const uint8_t* __restrict__ mraw,
    unsigned long long* __restrict__ best, unsigned* __restrict__ list,
    float* __restrict__ sigbuf, float* __restrict__ partials,
    int B, int N, int C, int M, int asgb, int nb) {
    if ((int)blockIdx.x < asgb) {
        int t = blockIdx.x * 4 + (threadIdx.x >> 6);
        if (t < B * M)
            assign_wave(ps, pb, gtb, gtl, mraw, best, list,
                        B, N, C, M, t, threadIdx.x & 63);
        return;
    }
    int bi = blockIdx.x - asgb;
    int b = bi / nb;
    int n = (bi % nb) * 256 + threadIdx.x;

    __shared__ int smask[256];
    __shared__ int s_notall;
    __shared__ float sredA[4], sredB[4];
    if (threadIdx.x == 0) s_notall = 0;
    __syncthreads();
    for (int c = threadIdx.x; c < C && c < 256; c += 256) {
        int v = mask_at(mraw, b * C + c);
        smask[c] = v;
        if (!v) s_notall = 1;          // benign race: all writers store 1
    }
    __syncthreads();
    bool allm = (s_notall == 0);

    int lane = threadIdx.x & 63, wid = threadIdx.x >> 6;
    float acc0 = 0.f, acc3 = 0.f;

    if (C == 80 && allm) {
        // coalesced 4-lane/row scheme: wave covers 64 rows in 4 passes of 16
        int wavebase = (bi % nb) * 256 + wid * 64;
        int j = lane & 3;
        const float* psb0 = ps + (size_t)b * N * 80;
#pragma unroll
        for (int p = 0; p < 4; ++p) {
            int row = wavebase + p * 16 + (lane >> 2);
            if (row < N) {
                const float4* rb = (const float4*)(psb0 + (size_t)row * 80);
                float4 q0 = rb[j], q1 = rb[4 + j], q2 = rb[8 + j],
                       q3 = rb[12 + j], q4 = rb[16 + j];
                float bce =
                    softplus_bce(q0.x) + softplus_bce(q0.y) + softplus_bce(q0.z) + softplus_bce(q0.w) +
                    softplus_bce(q1.x) + softplus_bce(q1.y) + softplus_bce(q1.z) + softplus_bce(q1.w) +
                    softplus_bce(q2.x) + softplus_bce(q2.y) + softplus_bce(q2.z) + softplus_bce(q2.w) +
                    softplus_bce(q3.x) + softplus_bce(q3.y) + softplus_bce(q3.z) + softplus_bce(q3.w) +
                    softplus_bce(q4.x) + softplus_bce(q4.y) + softplus_bce(q4.z) + softplus_bce(q4.w);
                float sm = fmaxf(fmaxf(fmaxf(q0.x, q0.y), fmaxf(q0.z, q0.w)),
                                 fmaxf(fmaxf(q1.x, q1.y), fmaxf(q1.z, q1.w)));
                sm = fmaxf(sm, fmaxf(fmaxf(q2.x, q2.y), fmaxf(q2.z, q2.w)));
                sm = fmaxf(sm, fmaxf(fmaxf(q3.x, q3.y), fmaxf(q3.z, q3.w)));
                sm = fmaxf(sm, fmaxf(fmaxf(q4.x, q4.y), fmaxf(q4.z, q4.w)));
                // reduce across the 4-lane row group
                bce += __shfl_xor(bce, 1, 64);
                bce += __shfl_xor(bce, 2, 64);
                sm = fmaxf(sm, __shfl_xor(sm, 1, 64));
                sm = fmaxf(sm, __shfl_xor(sm, 2, 64));
                if (j == 0) {
                    float sg = sigmoid_fast(sm);
                    sigbuf[(size_t)b * N + row] = sg;   // 16 lanes -> 64B contiguous
                    acc0 += bce;
                    acc3 += sg;
                }
            }
        }
    } else if (n < N) {
        const float* psr = ps + ((size_t)b * N + n) * C;
        float bce_sum = 0.f, smax = NEG_INF_F;
        if (allm) {
            int c4 = C & ~3;
            for (int c = 0; c < c4; c += 4) {
                float4 s4 = *(const float4*)(psr + c);
                bce_sum += softplus_bce(s4.x) + softplus_bce(s4.y) +
                           softplus_bce(s4.z) + softplus_bce(s4.w);
                smax = fmaxf(smax, fmaxf(fmaxf(s4.x, s4.y), fmaxf(s4.z, s4.w)));
            }
            for (int c = c4; c < C; ++c) {
                float s = psr[c];
                bce_sum += softplus_bce(s);
                smax = fmaxf(smax, s);
            }
        } else {
            for (int c = 0; c < C; ++c) {
                float s = psr[c];
                if (smask[c]) { bce_sum += softplus_bce(s); smax = fmaxf(smax, s); }
            }
        }
        float sg = sigmoid_fast(smax);
        sigbuf[(size_t)b * N + n] = sg;
        acc0 = bce_sum;
        acc3 = sg;
    }

    {
        float v0 = acc0, v3 = acc3;
        for (int off = 32; off > 0; off >>= 1) {
            v0 += __shfl_down(v0, off, 64);
            v3 += __shfl_down(v3, off, 64);
        }
        if (lane == 0) { sredA[wid] = v0; sredB[wid] = v3; }
    }
    __syncthreads();
    if (threadIdx.x == 0) {
        atomicAdd(&partials[b * 8 + 0], sredA[0] + sredA[1] + sredA[2] + sredA[3]);
        atomicAdd(&partials[b * 8 + 3], sredB[0] + sredB[1] + sredB[2] + sredB[3]);
    }
}

// ---- FUSED KERNEL B (compact): one thread per claim slot (B*M*TOPK total).
// Deduplication: decode the FINAL winner mg from best[b,n]; process only the
// entry whose claimant m == mg (exactly one per fg anchor). Computes the fg
// corrections (bce target term, CIoU, DFL, pos sum, fg count, MINUS
// sigmoid(smax) to turn partials[3] into the bg sum), accumulates via LDS
// atomics per (sample, slot), then last-block finalize.
__global__ __launch_bounds__(256, 1) void fused_b_k(
    const float* __restrict__ ps, const float* __restrict__ pb,
    const float* __restrict__ anch, const float* __restrict__ strd,
    const float* __restrict__ bd, const float* __restrict__ gtb,
    const int* __restrict__ gtl, const uint8_t* __restrict__ mraw,
    const unsigned long long* __restrict__ best, const float* __restrict__ sigbuf,
    const unsigned* __restrict__ list,
    float* __restrict__ partials, unsigned int* __restrict__ done_ctr,
    float* __restrict__ out, int B, int N, int C, int M) {
    __shared__ float sacc[MAXB_LDS * 8];
    __shared__ int s_last;
    bool use_lds = (B <= MAXB_LDS);
    if (use_lds)
        for (int i = threadIdx.x; i < B * 8; i += 256) sacc[i] = 0.f;
    __syncthreads();

    int idx = blockIdx.x * 256 + threadIdx.x;
    int cap = B * M * TOPK;
    bool active = false;
    int b = 0, n = 0, mg = 0;
    if (idx < cap) {
        unsigned e = list[idx];
        if (e != 0u) {
            n = (int)(e - 1u);
            b = idx / (M * TOPK);
            int m_claim = (idx / TOPK) % M;
            unsigned long long pk = best[(size_t)b * N + n];   // final winner
            mg = (int)(0xFFFFFFFFu - (unsigned)(pk & 0xFFFFFFFFull));
            active = (mg == m_claim);   // exactly one claimant matches
        }
    }

    if (active) {
        int lbl = gtl[b * M + mg];
        int m_lab = min(max(lbl, 0), C - 1);

        // burst the fg-path inputs: bd row (16x dwordx4), pb, gtb, anchor, stride
        const float* bdr = bd + ((size_t)b * N + n) * 64;
        const float4* bq4 = (const float4*)bdr;
        float4 bq[16];
#pragma unroll
        for (int i = 0; i < 16; ++i) bq[i] = bq4[i];
        float4 p = ((const float4*)pb)[(size_t)b * N + n];
        float4 g = ((const float4*)gtb)[(size_t)b * M + mg];
        float2 an = ((const float2*)anch)[n];
        float stv = strd[n];
        float slab = ps[((size_t)b * N + n) * C + m_lab];
        float sg = sigbuf[(size_t)b * N + n];

        float ov = iou_pair(p.x, p.y, p.z, p.w, g.x, g.y, g.z, g.w);
        float acc0 = -fmaxf(ov, 0.1f) * slab;   // -ps*tgt correction at c==m_lab
        float acc2 = sigmoid_fast(slab);
        float acc4 = ov;                        // miou_sum (iou(pb, tb=gtb))
        // CIoU(pb, gtb[mg])
        float w1 = p.z - p.x, h1 = p.w - p.y;
        float w2 = g.z - g.x, h2 = g.w - g.y;
        float cw = fmaxf(p.z, g.z) - fminf(p.x, g.x);
        float ch = fmaxf(p.w, g.w) - fminf(p.y, g.y);
        float c2 = cw * cw + ch * ch + EPSF;
        float dx = g.x + g.z - p.x - p.z;
        float dy = g.y + g.w - p.y - p.w;
        float rho2 = (dx * dx + dy * dy) * 0.25f;
        const float PI = 3.14159265358979323846f;
        float dv = atanf(w2 / (h2 + EPSF)) - atanf(w1 / (h1 + EPSF));
        float v = (4.f / (PI * PI)) * dv * dv;
        float a = v / (v - ov + 1.f + EPSF);
        float acc5 = 1.f - (ov - (rho2 / c2 + v * a));
        // DFL from the register-resident bd row
        float dall[4] = { (an.x - g.x) / stv, (an.y - g.y) / stv,
                          (g.z - an.x) / stv, (g.w - an.y) / stv };
        float dfl = 0.f;
#pragma unroll
        for (int k = 0; k < 4; ++k) {
            float4 q0 = bq[k * 4 + 0], q1 = bq[k * 4 + 1];
            float4 q2 = bq[k * 4 + 2], q3 = bq[k * 4 + 3];
            float mxv = fmaxf(fmaxf(fmaxf(q0.x, q0.y), fmaxf(q0.z, q0.w)),
                              fmaxf(fmaxf(q1.x, q1.y), fmaxf(q1.z, q1.w)));
            mxv = fmaxf(mxv, fmaxf(fmaxf(fmaxf(q2.x, q2.y), fmaxf(q2.z, q2.w)),
                                    fmaxf(fmaxf(q3.x, q3.y), fmaxf(q3.z, q3.w))));
            float se = exp2f((q0.x - mxv) * L2EF) + exp2f((q0.y - mxv) * L2EF) +
                       exp2f((q0.z - mxv) * L2EF) + exp2f((q0.w - mxv) * L2EF) +
                       exp2f((q1.x - mxv) * L2EF) + exp2f((q1.y - mxv) * L2EF) +
                       exp2f((q1.z - mxv) * L2EF) + exp2f((q1.w - mxv) * L2EF) +
                       exp2f((q2.x - mxv) * L2EF) + exp2f((q2.y - mxv) * L2EF) +
                       exp2f((q2.z - mxv) * L2EF) + exp2f((q2.w - mxv) * L2EF) +
                       exp2f((q3.x - mxv) * L2EF) + exp2f((q3.y - mxv) * L2EF) +
                       exp2f((q3.z - mxv) * L2EF) + exp2f((q3.w - mxv) * L2EF);
            float lse = mxv + log2f(se) * LN2F;
            float d = fminf(fmaxf(dall[k], 0.f), 14.99f);
            int tl = (int)d;
            int tr = min(tl + 1, 15);
            float wl = (float)tr - d;
            float xtl = bdr[k * 16 + tl];   // L1-hot re-read, avoids dyn reg index
            float xtr = bdr[k * 16 + tr];
            dfl += (lse - xtl) * wl + (lse - xtr) * (1.f - wl);
        }
        float accs[7] = { acc0, 1.f, acc2, -sg, acc4, acc5, dfl };
        if (use_lds) {
#pragma unroll
            for (int j = 0; j < 7; ++j) atomicAdd(&sacc[b * 8 + j], accs[j]);
        } else {
#pragma unroll
            for (int j = 0; j < 7; ++j) atomicAdd(&partials[b * 8 + j], accs[j]);
        }
    }
    __syncthreads();
    if (use_lds)
        for (int i = threadIdx.x; i < B * 8; i += 256)
            if (sacc[i] != 0.f) atomicAdd(&partials[i], sacc[i]);
    __syncthreads();

    // last-block-done finalize
    if (threadIdx.x == 0) {
        __threadfence();
        unsigned r = atomicAdd(done_ctr, 1u);
        s_last = (r == gridDim.x - 1u) ? 1 : 0;
    }
    __syncthreads();
    if (!s_last) return;
    if (threadIdx.x >= 64) return;
    __threadfence();   // acquire side

    int fl = threadIdx.x;
    float tm = 0, ti = 0, td = 0, tp = 0, tneg = 0, pos = 0, neg = 0, miou = 0;
    for (int s = fl; s < B; s += 64) {
        float vcs = 0.f;
        for (int c = 0; c < C; ++c) vcs += mask_at(mraw, s * C + c) ? 1.f : 0.f;
        const float* pr = partials + s * 8;
        float p0 = __hip_atomic_load(&pr[0], __ATOMIC_RELAXED, __HIP_MEMORY_SCOPE_AGENT);
        float p1 = __hip_atomic_load(&pr[1], __ATOMIC_RELAXED, __HIP_MEMORY_SCOPE_AGENT);
        float p2 = __hip_atomic_load(&pr[2], __ATOMIC_RELAXED, __HIP_MEMORY_SCOPE_AGENT);
        float p3 = __hip_atomic_load(&pr[3], __ATOMIC_RELAXED, __HIP_MEMORY_SCOPE_AGENT);
        float p4 = __hip_atomic_load(&pr[4], __ATOMIC_RELAXED, __HIP_MEMORY_SCOPE_AGENT);
        float p5 = __hip_atomic_load(&pr[5], __ATOMIC_RELAXED, __HIP_MEMORY_SCOPE_AGENT);
        float p6 = __hip_atomic_load(&pr[6], __ATOMIC_RELAXED, __HIP_MEMORY_SCOPE_AGENT);
        float cnt = p1;
        tm += p0 / ((float)N * fmaxf(vcs, 1.f));
        ti += (cnt > 0.f) ? p5 / fmaxf(cnt, 1.f) : 0.f;
        td += (cnt > 0.f) ? p6 / fmaxf(cnt * 4.f, 1.f) : 0.f;
        tp += cnt; tneg += (float)N - cnt;
        pos += p2; neg += p3; miou += p4;
    }
    for (int off = 32; off > 0; off >>= 1) {
        tm += __shfl_down(tm, off, 64);   ti += __shfl_down(ti, off, 64);
        td += __shfl_down(td, off, 64);   tp += __shfl_down(tp, off, 64);
        tneg += __shfl_down(tneg, off, 64); pos += __shfl_down(pos, off, 64);
        neg += __shfl_down(neg, off, 64); miou += __shfl_down(miou, off, 64);
    }
    if (fl == 0) {
        float Bf = (float)B;
        out[0] = (0.5f * tm + 7.5f * ti + 1.5f * td) / Bf;
        out[1] = tm / Bf;
        out[2] = ti / Bf;
        out[3] = td / Bf;
        out[4] = tp;
        out[5] = pos / fmaxf(tp, 1.f);
        out[6] = neg / fmaxf(tneg, 1.f);
        out[7] = miou / fmaxf(tp, 1.f);
    }
}

// ======================= generic fallback path (N != 8400) =======================
__global__ __launch_bounds__(256) void assign_topk_k(
    const float* __restrict__ ps, const float* __restrict__ pb,
    const float* __restrict__ anch, const float* __restrict__ gtb,
    const int* __restrict__ gtl, const uint8_t* __restrict__ mraw,
    unsigned long long* __restrict__ best, int B, int N, int C, int M) {
    int b = blockIdx.x % B;
    int m = blockIdx.x / B;

    __shared__ float cval[MAXCAND];
    __shared__ int   cidx[MAXCAND];
    __shared__ int   scnt;
    if (threadIdx.x == 0) scnt = 0;

    int lbl = gtl[b * M + m];
    int lab = min(max(lbl, 0), C - 1);
    bool valid = (lbl >= 0) && (lbl < C) && (mask_at(mraw, b * C + lab) != 0);
    __syncthreads();

    if (valid) {
        float4 g = ((const float4*)gtb)[(size_t)b * M + m];
        const float* psb = ps + (size_t)b * N * C + lab;
        const float4* pbb = (const float4*)pb + (size_t)b * N;
        for (int n = threadIdx.x; n < N; n += 256) {
            float2 a = ((const float2*)anch)[n];
            if (a.x < g.x || a.x > g.z || a.y < g.y || a.y > g.w) continue;
            float4 p = pbb[n];
            float iou = iou_pair(p.x, p.y, p.z, p.w, g.x, g.y, g.z, g.w);
            float s = psb[(size_t)n * C];
            float i3 = iou * iou * iou;
            float val = sigmoid_fast(s) * i3 * i3;
            int slot = atomicAdd(&scnt, 1);
            if (slot < MAXCAND) { cval[slot] = val; cidx[slot] = n; }
        }
    }
    __syncthreads();
    if (!valid || threadIdx.x >= 64) return;

    int total = min(scnt, MAXCAND);
    if (total == 0) return;
    int lane = threadIdx.x;

    float lv[TOPK];
    int   li[TOPK];
#pragma unroll
    for (int j = 0; j < TOPK; ++j) { lv[j] = NEG_INF_F; li[j] = -1; }
    for (int i = lane; i < total; i += 64) {
        float v = cval[i]; int ix = cidx[i];
        if (v > lv[TOPK - 1]) {
            bool placed = false;
#pragma unroll
            for (int j = TOPK - 1; j >= 1; --j) {
                if (!placed) {
                    if (v > lv[j - 1]) { lv[j] = lv[j - 1]; li[j] = li[j - 1]; }
                    else { lv[j] = v; li[j] = ix; placed = true; }
                }
            }
            if (!placed) { lv[0] = v; li[0] = ix; }
        }
    }

    unsigned key = 0xFFFFFFFFu - (unsigned)m;
    unsigned long long* bb = best + (size_t)b * N;
    int rounds = min(total, TOPK);
    for (int p = 0; p < rounds; ++p) {
        float bv = lv[0]; int bn = li[0];
        for (int off = 32; off > 0; off >>= 1) {
            float ov = __shfl_down(bv, off, 64);
            int   on = __shfl_down(bn, off, 64);
            if (ov > bv || (ov == bv && (unsigned)on < (unsigned)bn)) { bv = ov; bn = on; }
        }
        bv = __shfl(bv, 0, 64);
        bn = __shfl(bn, 0, 64);
        if (bn < 0) break;
        if (li[0] == bn) {
            unsigned long long pk =
                ((unsigned long long)__float_as_uint(lv[0]) << 32) | (unsigned long long)key;
            atomicMax(bb + bn, pk);
#pragma unroll
            for (int j = 0; j < TOPK - 1; ++j) { lv[j] = lv[j + 1]; li[j] = li[j + 1]; }
            lv[TOPK - 1] = NEG_INF_F; li[TOPK - 1] = -1;
        }
    }
}

__global__ __launch_bounds__(256, 1) void per_anchor_k(
    const float* __restrict__ ps, const float* __restrict__ pb,
    const float* __restrict__ anch, const float* __restrict__ strd,
    const float* __restrict__ bd, const float* __restrict__ gtb,
    const int* __restrict__ gtl, const uint8_t* __restrict__ mraw,
    const unsigned long long* __restrict__ best,
    float* __restrict__ partials, int B, int N, int C, int M) {
    int b = blockIdx.y;
    int n = blockIdx.x * 256 + threadIdx.x;

    __shared__ int smask[256];
    __shared__ int s_notall;
    __shared__ float sred[4 * 8];
    if (threadIdx.x == 0) s_notall = 0;
    __syncthreads();
    for (int c = threadIdx.x; c < C && c < 256; c += 256) {
        int v = mask_at(mraw, b * C + c);
        smask[c] = v;
        if (!v) s_notall = 1;
    }
    __syncthreads();
    bool allm = (s_notall == 0);

    float acc0 = 0, acc1 = 0, acc2 = 0, acc3 = 0, acc4 = 0, acc5 = 0, acc6 = 0;

    if (n < N) {
        unsigned long long pk = best[(size_t)b * N + n];
        bool fg = (pk != 0ull);
        int mg = fg ? (int)(0xFFFFFFFFu - (unsigned)(pk & 0xFFFFFFFFull)) : 0;
        int lbl = gtl[b * M + mg];
        int m_lab = min(max(lbl, 0), C - 1);

        const float* psr = ps + ((size_t)b * N + n) * C;
        float bce_sum = 0.f, smax = NEG_INF_F;

        if (allm) {
            int c4 = C & ~3;
            for (int c = 0; c < c4; c += 4) {
                float4 s4 = *(const float4*)(psr + c);
                bce_sum += softplus_bce(s4.x) + softplus_bce(s4.y) +
                           softplus_bce(s4.z) + softplus_bce(s4.w);
                smax = fmaxf(smax, fmaxf(fmaxf(s4.x, s4.y), fmaxf(s4.z, s4.w)));
            }
            for (int c = c4; c < C; ++c) {
                float s = psr[c];
                bce_sum += softplus_bce(s);
                smax = fmaxf(smax, s);
            }
        } else {
            for (int c = 0; c < C; ++c) {
                float s = psr[c];
                if (smask[c]) { bce_sum += softplus_bce(s); smax = fmaxf(smax, s); }
            }
        }

        acc1 = fg ? 1.f : 0.f;
        acc3 = fg ? 0.f : sigmoid_fast(smax);

        if (fg) {
            const float* bdr = bd + ((size_t)b * N + n) * 64;
            const float4* bq4 = (const float4*)bdr;
            float4 bq[16];
#pragma unroll
            for (int i = 0; i < 16; ++i) bq[i] = bq4[i];
            float4 p = ((const float4*)pb)[(size_t)b * N + n];
            float4 g = ((const float4*)gtb)[(size_t)b * M + mg];
            float2 an = ((const float2*)anch)[n];
            float stv = strd[n];
            float slab = psr[m_lab];

            float ov = iou_pair(p.x, p.y, p.z, p.w, g.x, g.y, g.z, g.w);
            bce_sum -= fmaxf(ov, 0.1f) * slab;
            acc2 = sigmoid_fast(slab);
            acc4 = ov;
            float w1 = p.z - p.x, h1 = p.w - p.y;
            float w2 = g.z - g.x, h2 = g.w - g.y;
            float cw = fmaxf(p.z, g.z) - fminf(p.x, g.x);
            float ch = fmaxf(p.w, g.w) - fminf(p.y, g.y);
            float c2 = cw * cw + ch * ch + EPSF;
            float dx = g.x + g.z - p.x - p.z;
            float dy = g.y + g.w - p.y - p.w;
            float rho2 = (dx * dx + dy * dy) * 0.25f;
            const float PI = 3.14159265358979323846f;
            float dv = atanf(w2 / (h2 + EPSF)) - atanf(w1 / (h1 + EPSF));
            float v = (4.f / (PI * PI)) * dv * dv;
            float a = v / (v - ov + 1.f + EPSF);
            acc5 = 1.f - (ov - (rho2 / c2 + v * a));
            float dall[4] = { (an.x - g.x) / stv, (an.y - g.y) / stv,
                              (g.z - an.x) / stv, (g.w - an.y) / stv };
            float dfl = 0.f;
#pragma unroll
            for (int k = 0; k < 4; ++k) {
                float4 q0 = bq[k * 4 + 0], q1 = bq[k * 4 + 1];
                float4 q2 = bq[k * 4 + 2], q3 = bq[k * 4 + 3];
                float mxv = fmaxf(fmaxf(fmaxf(q0.x, q0.y), fmaxf(q0.z, q0.w)),
                                  fmaxf(fmaxf(q1.x, q1.y), fmaxf(q1.z, q1.w)));
                mxv = fmaxf(mxv, fmaxf(fmaxf(fmaxf(q2.x, q2.y), fmaxf(q2.z, q2.w)),
                                        fmaxf(fmaxf(q3.x, q3.y), fmaxf(q3.z, q3.w))));
                float se = exp2f((q0.x - mxv) * L2EF) + exp2f((q0.y - mxv) * L2EF) +
                           exp2f((q0.z - mxv) * L2EF) + exp2f((q0.w - mxv) * L2EF) +
                           exp2f((q1.x - mxv) * L2EF) + exp2f((q1.y - mxv) * L2EF) +
                           exp2f((q1.z - mxv) * L2EF) + exp2f((q1.w - mxv) * L2EF) +
                           exp2f((q2.x - mxv) * L2EF) + exp2f((q2.y - mxv) * L2EF) +
                           exp2f((q2.z - mxv) * L2EF) + exp2f((q2.w - mxv) * L2EF) +
                           exp2f((q3.x - mxv) * L2EF) + exp2f((q3.y - mxv) * L2EF) +
                           exp2f((q3.z - mxv) * L2EF) + exp2f((q3.w - mxv) * L2EF);
                float lse = mxv + log2f(se) * LN2F;
                float d = fminf(fmaxf(dall[k], 0.f), 14.99f);
                int tl = (int)d;
                int tr = min(tl + 1, 15);
                float wl = (float)tr - d;
                float xtl = bdr[k * 16 + tl];
                float xtr = bdr[k * 16 + tr];
                dfl += (lse - xtl) * wl + (lse - xtr) * (1.f - wl);
            }
            acc6 = dfl;
        }
        acc0 = bce_sum;
    }

    int lane = threadIdx.x & 63, wid = threadIdx.x >> 6;
    float accs[7] = { acc0, acc1, acc2, acc3, acc4, acc5, acc6 };
#pragma unroll
    for (int j = 0; j < 7; ++j) {
        float v = accs[j];
        for (int off = 32; off > 0; off >>= 1) v += __shfl_down(v, off, 64);
        if (lane == 0) sred[wid * 8 + j] = v;
    }
    __syncthreads();
    if (threadIdx.x < 7) {
        float s = sred[0 * 8 + threadIdx.x] + sred[1 * 8 + threadIdx.x] +
                  sred[2 * 8 + threadIdx.x] + sred[3 * 8 + threadIdx.x];
        atomicAdd(&partials[b * 8 + threadIdx.x], s);
    }
}

__global__ void finalize_k(const float* __restrict__ partials, const uint8_t* __restrict__ mraw,
                           float* __restrict__ out, int B, int N, int C) {
    int lane = threadIdx.x;
    float tm = 0, ti = 0, td = 0, tp = 0, tneg = 0, pos = 0, neg = 0, miou = 0;
    if (lane < B) {
        float vcs = 0.f;
        for (int c = 0; c < C; ++c) vcs += mask_at(mraw, lane * C + c) ? 1.f : 0.f;
        const float* pr = partials + lane * 8;
        float cnt = pr[1];
        tm = pr[0] / ((float)N * fmaxf(vcs, 1.f));
        ti = (cnt > 0.f) ? pr[5] / fmaxf(cnt, 1.f) : 0.f;
        td = (cnt > 0.f) ? pr[6] / fmaxf(cnt * 4.f, 1.f) : 0.f;
        tp = cnt; tneg = (float)N - cnt;
        pos = pr[2]; neg = pr[3]; miou = pr[4];
    }
    for (int off = 32; off > 0; off >>= 1) {
        tm += __shfl_down(tm, off, 64);   ti += __shfl_down(ti, off, 64);
        td += __shfl_down(td, off, 64);   tp += __shfl_down(tp, off, 64);
        tneg += __shfl_down(tneg, off, 64); pos += __shfl_down(pos, off, 64);
        neg += __shfl_down(neg, off, 64); miou += __shfl_down(miou, off, 64);
    }
    if (lane == 0) {
        float Bf = (float)B;
        out[0] = (0.5f * tm + 7.5f * ti + 1.5f * td) / Bf;
        out[1] = tm / Bf;
        out[2] = ti / Bf;
        out[3] = td / Bf;
        out[4] = tp;
        out[5] = pos / fmaxf(tp, 1.f);
        out[6] = neg / fmaxf(tneg, 1.f);
        out[7] = miou / fmaxf(tp, 1.f);
    }
}

extern "C" void kernel_launch(void* const* d_in, const int* in_sizes, int n_in,
                              void* d_out, int out_size, void* d_ws, size_t ws_size,
                              hipStream_t stream) {
    const float* ps   = (const float*)d_in[0];   // (B,N,C)
    const float* pb   = (const float*)d_in[1];   // (B,N,4)
    const float* anch = (const float*)d_in[2];   // (N,2)
    const float* strd = (const float*)d_in[3];   // (N,1)
    const float* bd   = (const float*)d_in[4];   // (B,N,64)
    const float* gtb  = (const float*)d_in[5];   // (B,M,4)
    const int*   gtl  = (const int*)d_in[6];     // (B,M)
    const uint8_t* cmsk = (const uint8_t*)d_in[7]; // (B,C) bool

    int N = in_sizes[2] / 2;
    int B = in_sizes[1] / (4 * N);
    int C = in_sizes[0] / (B * N);
    int M = in_sizes[6] / B;

    // workspace layout: [best | partials | ctr | list (all zeroed) | sigbuf]
    size_t bestBytes = (size_t)B * N * sizeof(unsigned long long);
    size_t off1 = (bestBytes + 255) & ~(size_t)255;                 // partials
    size_t partBytes = (size_t)B * 8 * sizeof(float);
    size_t off2 = (off1 + partBytes + 255) & ~(size_t)255;          // done ctr
    size_t off3 = off2 + 256;                                       // list
    size_t listBytes = (size_t)B * M * TOPK * sizeof(unsigned);
    size_t zeroBytes = (off3 + listBytes + 255) & ~(size_t)255;
    unsigned long long* best = (unsigned long long*)d_ws;
    float* partials = (float*)((char*)d_ws + off1);
    unsigned int* done_ctr = (unsigned int*)((char*)d_ws + off2);
    unsigned int* list = (unsigned int*)((char*)d_ws + off3);
    float* sigbuf = (float*)((char*)d_ws + zeroBytes);              // no init needed

    hipMemsetAsync(d_ws, 0, zeroBytes, stream);

    int nb = (N + 255) / 256;
    if (N == 8400) {
        int asgb = (B * M + 3) / 4;
        fused_a_k<<<asgb + B * nb, 256, 0, stream>>>(ps, pb, gtb, gtl, cmsk,
                                                     best, list, sigbuf,
                                                     partials, B, N, C, M, asgb, nb);
        int cap = B * M * TOPK;
        int nblk = (cap + 255) / 256;
        fused_b_k<<<nblk, 256, 0, stream>>>(ps, pb, anch, strd, bd, gtb, gtl, cmsk,
                                            best, sigbuf, list,
                                            partials, done_ctr, (float*)d_out, B, N, C, M);
    } else {
        assign_topk_k<<<B * M, 256, 0, stream>>>(ps, pb, anch, gtb, gtl, cmsk, best, B, N, C, M);
        dim3 gB(nb, B);
        per_anchor_k<<<gB, 256, 0, stream>>>(ps, pb, anch, strd, bd, gtb, gtl, cmsk, best,
                                             partials, B, N, C, M);
        finalize_k<<<1, 64, 0, stream>>>(partials, cmsk, (float*)d_out, B, N, C);
    }
}